// Round 16
// baseline (341.146 us; speedup 1.0000x reference)
//
#include <hip/hip_runtime.h>
#include <math.h>

#define BB 256
#define SS 30
#define CC 62
#define LL 169
#define OG 64
#define OH 64
#define KK1 64
#define KK2 32
#define KK3 14
#define FLEN 108     // 64+32+14-2

typedef __attribute__((ext_vector_type(8))) short s16x8;
typedef __attribute__((ext_vector_type(4))) float f32x4;

__device__ __forceinline__ unsigned short f2bf(float f) {
    unsigned u = __float_as_uint(f);
    u += 0x7fffu + ((u >> 16) & 1u);        // RTNE
    return (unsigned short)(u >> 16);
}

// ---------------- setup stage 1 (1 block): weights prep + Bm ----------------
__global__ __launch_bounds__(1024) void k_setup1(
        const float* __restrict__ dw1, const float* __restrict__ dw1b,
        const float* __restrict__ pw1, const float* __restrict__ pw1b,
        const float* __restrict__ dw2, const float* __restrict__ dw2b,
        const float* __restrict__ pw2, const float* __restrict__ pw2b,
        const float* __restrict__ dw3, const float* __restrict__ dw3b,
        const float* __restrict__ pw3, const float* __restrict__ pw3b,
        const float* __restrict__ Wr, const float* __restrict__ Wrb, const float* __restrict__ br,
        const float* __restrict__ Wu, const float* __restrict__ Wub, const float* __restrict__ bu,
        const float* __restrict__ Wc, const float* __restrict__ Wcb, const float* __restrict__ bc,
        float* __restrict__ Bmg, float* __restrict__ WtAll,
        float* __restrict__ bias192, float* __restrict__ beff) {
    __shared__ float g23[CC * KK3];
    __shared__ float Am[CC * 45];
    __shared__ float by2[CC], vals[CC];
    int tid = threadIdx.x;

    for (int idx = tid; idx < OG * 192; idx += 1024) {
        int i = idx / 192, q = idx - i * 192;
        int gate = q >> 6, f = q & 63;
        const float* W = gate == 0 ? Wr : (gate == 1 ? Wu : Wc);
        WtAll[idx] = W[f * (OG + OH) + i];
    }
    if (tid < 192) {
        int gate = tid >> 6, f = tid & 63;
        const float* Wb = gate == 0 ? Wrb : (gate == 1 ? Wub : Wcb);
        const float* bb = gate == 0 ? br  : (gate == 1 ? bu  : bc);
        bias192[tid] = Wb[f] + bb[f];
    }
    for (int idx = tid; idx < CC * KK3; idx += 1024) {
        int c1 = idx / KK3, k3 = idx - c1 * KK3;
        float s = 0.f;
        for (int c2 = 0; c2 < CC; ++c2)
            s += pw3[61 * CC + c2] * pw2[c2 * CC + c1] * dw3[c2 * KK3 + k3];
        g23[idx] = s;
    }
    if (tid < CC) {
        int c1 = tid;
        float bz1 = pw1b[c1];
        for (int c0 = 0; c0 < CC; ++c0) bz1 += pw1[c1 * CC + c0] * dw1b[c0];
        float s2 = 0.f;
        for (int k = 0; k < KK2; ++k) s2 += dw2[c1 * KK2 + k];
        by2[c1] = dw2b[c1] + bz1 * s2;
    }
    __syncthreads();
    if (tid < CC) {
        int c2 = tid;
        float bz2 = pw2b[c2];
        for (int c1 = 0; c1 < CC; ++c1) bz2 += pw2[c2 * CC + c1] * by2[c1];
        float s3 = 0.f;
        for (int k = 0; k < KK3; ++k) s3 += dw3[c2 * KK3 + k];
        vals[c2] = pw3[61 * CC + c2] * (dw3b[c2] + bz2 * s3);
    }
    for (int idx = tid; idx < CC * 45; idx += 1024) {
        int c1 = idx / 45, m = idx - c1 * 45;
        int k2lo = max(0, m - (KK3 - 1));
        int k2hi = min(KK2 - 1, m);
        float s = 0.f;
        for (int k2 = k2lo; k2 <= k2hi; ++k2)
            s += dw2[c1 * KK2 + k2] * g23[c1 * KK3 + (m - k2)];
        Am[idx] = s;
    }
    __syncthreads();
    if (tid == 0) {
        float s = pw3b[61];
        for (int c2 = 0; c2 < CC; ++c2) s += vals[c2];
        *beff = s;
    }
    for (int idx = tid; idx < CC * 45; idx += 1024) {
        int c0 = idx / 45, m = idx - c0 * 45;
        float s = 0.f;
        for (int c1 = 0; c1 < CC; ++c1) s += pw1[c1 * CC + c0] * Am[c1 * 45 + m];
        Bmg[idx] = s;
    }
}

// ---------------- setup stage 2 (64 blocks): Ftb[o][c0] ----------------
__global__ __launch_bounds__(128) void k_setupF(
        const float* __restrict__ Bmg, const float* __restrict__ dw1,
        unsigned short* __restrict__ Ftb) {
    __shared__ float Bl[45];
    int c0 = blockIdx.x;
    int o = threadIdx.x;
    if (c0 < CC && o < 45) Bl[o] = Bmg[c0 * 45 + o];
    __syncthreads();
    if (o >= 112) return;
    float s = 0.f;
    if (c0 < CC && o < FLEN) {
        int mlo = max(0, o - (KK1 - 1));
        int mhi = min(44, o);
        for (int m = mlo; m <= mhi; ++m)
            s += Bl[m] * dw1[c0 * KK1 + (o - m)];
    }
    Ftb[o * 64 + c0] = f2bf(s);
}

// ---------------- main: one block per (b,t); coalesced chunk pipeline + MFMA + fused gates ----
// chunk ch (8 channels, last 6): coalesced dwordx2 loads -> regs -> linear LDS buf ->
// conflict-free transpose/pack -> swizzled xT. vmcnt literal counted; raw barriers
// (manual lgkmcnt(0), NO vmcnt drain) keep next chunk's loads in flight.
#define CH_ISSUE(ch) do {                                                          \
    const int nd2 = ((ch) < 7) ? 676 : 507;                                        \
    const float* cb = xg + 1352 * (ch);                                            \
    _Pragma("unroll")                                                              \
    for (int j = 0; j < 3; ++j) {                                                  \
        int pos = tid + j * 256; if (pos > nd2 - 1) pos = nd2 - 1;                 \
        asm volatile("global_load_dwordx2 %0, %1, off"                             \
                     : "=v"(SL[(ch) & 1][j]) : "v"(cb + 2 * pos));                 \
    }                                                                              \
} while (0)

#define CH_CONSUME(ch, VM) do {                                                    \
    asm volatile("s_waitcnt vmcnt(" VM ")"                                         \
        : "+v"(SL[(ch) & 1][0]), "+v"(SL[(ch) & 1][1]), "+v"(SL[(ch) & 1][2]));    \
    {                                                                              \
        const int nd2 = ((ch) < 7) ? 676 : 507;                                    \
        uint2* cb2 = (uint2*)chunkbuf[(ch) & 1];                                   \
        _Pragma("unroll")                                                          \
        for (int j = 0; j < 3; ++j) {                                              \
            int pos = tid + j * 256; if (pos > nd2 - 1) pos = nd2 - 1;             \
            cb2[pos] = SL[(ch) & 1][j];                                            \
        }                                                                          \
    }                                                                              \
    asm volatile("s_waitcnt lgkmcnt(0)" ::: "memory");                             \
    __builtin_amdgcn_sched_barrier(0);                                             \
    __builtin_amdgcn_s_barrier();                                                  \
    {                                                                              \
        const int ncp = ((ch) < 7) ? 4 : 3;                                        \
        const unsigned* cb = (const unsigned*)chunkbuf[(ch) & 1];                  \
        int cpL = tid & 3, lb = tid >> 2;                                          \
        _Pragma("unroll")                                                          \
        for (int it = 0; it < 3; ++it) {                                           \
            int l = lb + 64 * it;                                                  \
            if (l < LL && cpL < ncp) {                                             \
                unsigned lo = cb[(2 * cpL) * LL + l];                              \
                unsigned hi = cb[(2 * cpL + 1) * LL + l];                          \
                unsigned v;                                                        \
                asm("v_cvt_pk_bf16_f32 %0, %1, %2" : "=v"(v)                       \
                    : "v"(__uint_as_float(lo)), "v"(__uint_as_float(hi)));         \
                int cp = (ch) * 4 + cpL;                                           \
                xTu[(l * 32 + cp) ^ ((l & 7) << 2)] = v;                           \
            }                                                                      \
        }                                                                          \
    }                                                                              \
    asm volatile("s_waitcnt lgkmcnt(0)" ::: "memory");                             \
    __builtin_amdgcn_sched_barrier(0);                                             \
    __builtin_amdgcn_s_barrier();                                                  \
} while (0)

__global__ __launch_bounds__(256, 3) void k_main(
        const float* __restrict__ x, const float* __restrict__ adj,
        const unsigned short* __restrict__ Ftb, const float* __restrict__ beff_p,
        const float* __restrict__ gcnw, const float* __restrict__ gcnb,
        const float* __restrict__ WtAll, const float* __restrict__ bias192,
        float* __restrict__ gates) {
    __shared__ __align__(16) unsigned short xT[176 * 64];   // 22528 B swizzled [l][c] bf16
    __shared__ __align__(16) char chunkbuf[2][5408];        // 10816 B rolling f32 chunks
    __shared__ float dacc[4][64];
    __shared__ __align__(16) unsigned adjbf[32];
    __shared__ float wxl[176];
    __shared__ float gpart[4][64];
    __shared__ float Gl[64];
    int bt = blockIdx.x;
    int tid = threadIdx.x;
    int lane = tid & 63, wid = tid >> 6;
    int col = lane & 15, rb4 = lane >> 4;
    unsigned* xTu = (unsigned*)xT;
    const float* xg = x + (size_t)bt * (CC * LL);

    // aux loads FIRST (older vmcnt entries -> counted waits stay sufficient)
    float be = *beff_p;                                        // SMEM
    float2 arow2 = make_float2(0.f, 0.f);
    if (tid < 31) arow2 = *(const float2*)(adj + 61 * CC + 2 * tid);
    const unsigned short* ap0 = Ftb + ((wid * 16 + col) * 64 + rb4 * 8);
    s16x8 pa0 = *(const s16x8*)ap0;
    s16x8 pa1 = *(const s16x8*)(ap0 + 32);
    int mt2c = wid + 4 < 7 ? wid + 4 : 6;
    const unsigned short* ap1 = Ftb + ((mt2c * 16 + col) * 64 + rb4 * 8);
    s16x8 pb0 = *(const s16x8*)(ap1);
    s16x8 pb1 = *(const s16x8*)(ap1 + 32);
    __builtin_amdgcn_sched_barrier(0);

    uint2 SL[2][3];
    CH_ISSUE(0); CH_ISSUE(1);
    // zero pads (col dword 31, rows>=169) + dacc while loads fly
    for (int i = tid; i < 169; i += 256) xTu[(i * 32 + 31) ^ ((i & 7) << 2)] = 0;
    for (int i = tid; i < 224; i += 256) {
        int r = 169 + (i >> 5), dd = i & 31;
        xTu[(r * 32 + dd) ^ ((r & 7) << 2)] = 0;
    }
    ((float*)dacc)[tid] = 0.f;

    CH_CONSUME(0, "3"); CH_ISSUE(2);
    CH_CONSUME(1, "3"); CH_ISSUE(3);
    CH_CONSUME(2, "3"); CH_ISSUE(4);
    CH_CONSUME(3, "3"); CH_ISSUE(5);
    CH_CONSUME(4, "3"); CH_ISSUE(6);
    CH_CONSUME(5, "3"); CH_ISSUE(7);
    CH_CONSUME(6, "3");
    CH_CONSUME(7, "0");

    // ---- band MFMA: wave wid handles mt in {wid, wid+4}; atomics -> dacc[rb4][j] ----
    // high-c half read is (bbyte ^ 64): bbyte already row-XOR'd; pre-swizzle bit6==0.
    f32x4 zacc[5];
    #pragma unroll
    for (int d = 0; d < 5; ++d) zacc[d] = (f32x4){0.f, 0.f, 0.f, 0.f};
    int kb = rb4 * 16;
    int xr = (lane & 7) << 4;
    #pragma unroll
    for (int h = 0; h < 2; ++h) {
        int mt = wid + 4 * h;
        if (mt < 7) {
            s16x8 a0 = h == 0 ? pa0 : pb0;
            s16x8 a1 = h == 0 ? pa1 : pb1;
            #pragma unroll
            for (int d = 0; d < 5; ++d) {
                int nt = mt + d;
                int bbyte = ((nt * 16 + col) * 128 + kb) ^ xr;
                s16x8 b0 = *(const s16x8*)((const char*)xT + bbyte);
                s16x8 b1 = *(const s16x8*)((const char*)xT + (bbyte ^ 64));
                zacc[d] = __builtin_amdgcn_mfma_f32_16x16x32_bf16(a0, b0, zacc[d], 0, 0, 0);
                zacc[d] = __builtin_amdgcn_mfma_f32_16x16x32_bf16(a1, b1, zacc[d], 0, 0, 0);
            }
        }
    }
    int jc = col - rb4 * 4;
    #pragma unroll
    for (int d = 0; d < 5; ++d) {
        #pragma unroll
        for (int r = 0; r < 4; ++r) {
            int j = 16 * d + jc - r;
            if ((unsigned)j < 62u) atomicAdd(&dacc[rb4][j], zacc[d][r]);
        }
    }
    __syncthreads();

    // ---- fused sigmoid + bf16 pack ----
    if (tid < 32) {
        unsigned pk = 0;
        if (tid < 31) {
            int j0 = 2 * tid;
            float2 g0 = *(const float2*)(&dacc[0][j0]);
            float2 g1 = *(const float2*)(&dacc[1][j0]);
            float2 g2 = *(const float2*)(&dacc[2][j0]);
            float2 g3 = *(const float2*)(&dacc[3][j0]);
            float dv0 = (g0.x + g1.x) + (g2.x + g3.x) + be + arow2.x;
            float dv1 = (g0.y + g1.y) + (g2.y + g3.y) + be + arow2.y;
            float s0 = 1.f / (1.f + __expf(-dv0));
            float s1 = 1.f / (1.f + __expf(-dv1));
            asm("v_cvt_pk_bf16_f32 %0, %1, %2" : "=v"(pk) : "v"(s0), "v"(s1));
        }
        adjbf[tid] = pk;
    }
    __syncthreads();

    // ---- wx via MFMA -> wxl (LDS) ----
    {
        s16x8 wa0 = *(const s16x8*)(adjbf + rb4 * 4);
        s16x8 wa1 = *(const s16x8*)(adjbf + 16 + rb4 * 4);
        #pragma unroll
        for (int q = 0; q < 3; ++q) {
            int nt = wid + 4 * q;
            if (nt < 11) {
                int bbyte = ((nt * 16 + col) * 128 + kb) ^ xr;
                s16x8 b0 = *(const s16x8*)((const char*)xT + bbyte);
                s16x8 b1 = *(const s16x8*)((const char*)xT + (bbyte ^ 64));
                f32x4 wacc = {0.f, 0.f, 0.f, 0.f};
                wacc = __builtin_amdgcn_mfma_f32_16x16x32_bf16(wa0, b0, wacc, 0, 0, 0);
                wacc = __builtin_amdgcn_mfma_f32_16x16x32_bf16(wa1, b1, wacc, 0, 0, 0);
                if (rb4 == 0) wxl[nt * 16 + col] = wacc[0];
            }
        }
    }
    __syncthreads();

    // ---- G = wx @ gcn_w + gcn_b (in-block, weights from L2) ----
    {
        int f = tid & 63, lq = tid >> 6;
        float s = 0.f;
        for (int l = lq; l < LL; l += 4) s += wxl[l] * gcnw[l * OG + f];
        gpart[lq][f] = s;
    }
    __syncthreads();
    if (tid < OG)
        Gl[tid] = gcnb[tid] + gpart[0][tid] + gpart[1][tid] + gpart[2][tid] + gpart[3][tid];
    __syncthreads();

    // ---- gates[bt][192] = G @ W^T + biases (coalesced global write) ----
    if (tid < 192) {
        float s = bias192[tid];
        #pragma unroll 16
        for (int k = 0; k < OG; ++k) s += Gl[k] * WtAll[k * 192 + tid];
        gates[(size_t)bt * 192 + tid] = s;
    }
}

// ---------------- sequential GRU scan over t: one block per batch row ----------------
__global__ __launch_bounds__(256) void k_scan(
        const float* __restrict__ gates,
        const float* __restrict__ Wr, const float* __restrict__ Wu, const float* __restrict__ Wc,
        float* __restrict__ out) {
    __shared__ float hl[OH], rhl[OH];
    int b = blockIdx.x;
    int tid = threadIdx.x;
    int f = tid >> 2, q = tid & 3;
    float wr[16], wu[16], wc[16];
    #pragma unroll
    for (int i = 0; i < 16; ++i) {
        int col = OG + q * 16 + i;
        wr[i] = Wr[f * (OG + OH) + col];
        wu[i] = Wu[f * (OG + OH) + col];
        wc[i] = Wc[f * (OG + OH) + col];
    }
    float h = 0.f;
    if (tid < OH) hl[tid] = 0.f;
    __syncthreads();
    for (int t = 0; t < SS; ++t) {
        const float* gp = gates + ((size_t)b * SS + t) * 192;
        float gr = gp[f];
        float gu = gp[64 + f];
        float gc = gp[128 + f];
        float rv = 0.f, uv = 0.f;
        #pragma unroll
        for (int i = 0; i < 16; ++i) {
            float hv = hl[q * 16 + i];
            rv += wr[i] * hv;
            uv += wu[i] * hv;
        }
        rv += __shfl_xor(rv, 1); rv += __shfl_xor(rv, 2);
        uv += __shfl_xor(uv, 1); uv += __shfl_xor(uv, 2);
        float r = 1.f / (1.f + __expf(-(rv + gr)));
        float u = 1.f / (1.f + __expf(-(uv + gu)));
        if (q == 0) rhl[f] = r * h;
        __syncthreads();
        float cv = 0.f;
        #pragma unroll
        for (int i = 0; i < 16; ++i) cv += wc[i] * rhl[q * 16 + i];
        cv += __shfl_xor(cv, 1); cv += __shfl_xor(cv, 2);
        float cc = tanhf(cv + gc);
        if (q == 0) {
            h = u * h + (1.f - u) * cc;
            hl[f] = h;
        }
        __syncthreads();
    }
    if (q == 0) out[b * OH + f] = h;
}

extern "C" void kernel_launch(void* const* d_in, const int* in_sizes, int n_in,
                              void* d_out, int out_size, void* d_ws, size_t ws_size,
                              hipStream_t stream) {
    const float* x    = (const float*)d_in[0];
    const float* adj  = (const float*)d_in[1];
    const float* dw1w = (const float*)d_in[2];
    const float* dw1b = (const float*)d_in[3];
    const float* pw1w = (const float*)d_in[4];
    const float* pw1b = (const float*)d_in[5];
    const float* dw2w = (const float*)d_in[6];
    const float* dw2b = (const float*)d_in[7];
    const float* pw2w = (const float*)d_in[8];
    const float* pw2b = (const float*)d_in[9];
    const float* dw3w = (const float*)d_in[10];
    const float* dw3b = (const float*)d_in[11];
    const float* pw3w = (const float*)d_in[12];
    const float* pw3b = (const float*)d_in[13];
    const float* gcnw = (const float*)d_in[14];
    const float* gcnb = (const float*)d_in[15];
    const float* Wrw  = (const float*)d_in[16];
    const float* Wrb  = (const float*)d_in[17];
    const float* Wuw  = (const float*)d_in[18];
    const float* Wub  = (const float*)d_in[19];
    const float* Wcw  = (const float*)d_in[20];
    const float* Wcb  = (const float*)d_in[21];
    const float* br   = (const float*)d_in[22];
    const float* bu   = (const float*)d_in[23];
    const float* bc   = (const float*)d_in[24];
    float* out = (float*)d_out;

    char* ws = (char*)d_ws;
    unsigned short* Ftb = (unsigned short*)(ws + 0);        // 14336 B
    float* WtAll        = (float*)(ws + 14336);             // 49152 B
    float* bias192      = (float*)(ws + 63488);             // 768 B
    float* beff         = (float*)(ws + 64256);             // 4 B
    float* Bmg          = (float*)(ws + 64320);             // 11160 B
    float* gates        = (float*)(ws + 76800);             // 7680*192*4 = 5898240 B
    (void)ws_size; (void)in_sizes; (void)n_in; (void)out_size;

    k_setup1<<<1, 1024, 0, stream>>>(dw1w, dw1b, pw1w, pw1b, dw2w, dw2b, pw2w, pw2b,
                                     dw3w, dw3b, pw3w, pw3b,
                                     Wrw, Wrb, br, Wuw, Wub, bu, Wcw, Wcb, bc,
                                     Bmg, WtAll, bias192, beff);
    k_setupF<<<64, 128, 0, stream>>>(Bmg, dw1w, Ftb);
    k_main<<<BB * SS, 256, 0, stream>>>(x, adj, Ftb, beff, gcnw, gcnb,
                                        WtAll, bias192, gates);
    k_scan<<<BB, 256, 0, stream>>>(gates, Wrw, Wuw, Wcw, out);
}

// Round 17
// 310.020 us; speedup vs baseline: 1.1004x; 1.1004x over previous
//
#include <hip/hip_runtime.h>
#include <math.h>

#define BB 256
#define SS 30
#define CC 62
#define LL 169
#define OG 64
#define OH 64
#define KK1 64
#define KK2 32
#define KK3 14
#define FLEN 108     // 64+32+14-2

typedef __attribute__((ext_vector_type(8))) short s16x8;
typedef __attribute__((ext_vector_type(4))) float f32x4;

__device__ __forceinline__ unsigned short f2bf(float f) {
    unsigned u = __float_as_uint(f);
    u += 0x7fffu + ((u >> 16) & 1u);        // RTNE
    return (unsigned short)(u >> 16);
}

// ---------------- setup stage 1 (1 block): weights prep + Bm ----------------
__global__ __launch_bounds__(1024) void k_setup1(
        const float* __restrict__ dw1, const float* __restrict__ dw1b,
        const float* __restrict__ pw1, const float* __restrict__ pw1b,
        const float* __restrict__ dw2, const float* __restrict__ dw2b,
        const float* __restrict__ pw2, const float* __restrict__ pw2b,
        const float* __restrict__ dw3, const float* __restrict__ dw3b,
        const float* __restrict__ pw3, const float* __restrict__ pw3b,
        const float* __restrict__ Wr, const float* __restrict__ Wrb, const float* __restrict__ br,
        const float* __restrict__ Wu, const float* __restrict__ Wub, const float* __restrict__ bu,
        const float* __restrict__ Wc, const float* __restrict__ Wcb, const float* __restrict__ bc,
        float* __restrict__ Bmg, float* __restrict__ WtAll,
        float* __restrict__ bias192, float* __restrict__ beff) {
    __shared__ float g23[CC * KK3];
    __shared__ float Am[CC * 45];
    __shared__ float by2[CC], vals[CC];
    int tid = threadIdx.x;

    for (int idx = tid; idx < OG * 192; idx += 1024) {
        int i = idx / 192, q = idx - i * 192;
        int gate = q >> 6, f = q & 63;
        const float* W = gate == 0 ? Wr : (gate == 1 ? Wu : Wc);
        WtAll[idx] = W[f * (OG + OH) + i];
    }
    if (tid < 192) {
        int gate = tid >> 6, f = tid & 63;
        const float* Wb = gate == 0 ? Wrb : (gate == 1 ? Wub : Wcb);
        const float* bb = gate == 0 ? br  : (gate == 1 ? bu  : bc);
        bias192[tid] = Wb[f] + bb[f];
    }
    for (int idx = tid; idx < CC * KK3; idx += 1024) {
        int c1 = idx / KK3, k3 = idx - c1 * KK3;
        float s = 0.f;
        for (int c2 = 0; c2 < CC; ++c2)
            s += pw3[61 * CC + c2] * pw2[c2 * CC + c1] * dw3[c2 * KK3 + k3];
        g23[idx] = s;
    }
    if (tid < CC) {
        int c1 = tid;
        float bz1 = pw1b[c1];
        for (int c0 = 0; c0 < CC; ++c0) bz1 += pw1[c1 * CC + c0] * dw1b[c0];
        float s2 = 0.f;
        for (int k = 0; k < KK2; ++k) s2 += dw2[c1 * KK2 + k];
        by2[c1] = dw2b[c1] + bz1 * s2;
    }
    __syncthreads();
    if (tid < CC) {
        int c2 = tid;
        float bz2 = pw2b[c2];
        for (int c1 = 0; c1 < CC; ++c1) bz2 += pw2[c2 * CC + c1] * by2[c1];
        float s3 = 0.f;
        for (int k = 0; k < KK3; ++k) s3 += dw3[c2 * KK3 + k];
        vals[c2] = pw3[61 * CC + c2] * (dw3b[c2] + bz2 * s3);
    }
    for (int idx = tid; idx < CC * 45; idx += 1024) {
        int c1 = idx / 45, m = idx - c1 * 45;
        int k2lo = max(0, m - (KK3 - 1));
        int k2hi = min(KK2 - 1, m);
        float s = 0.f;
        for (int k2 = k2lo; k2 <= k2hi; ++k2)
            s += dw2[c1 * KK2 + k2] * g23[c1 * KK3 + (m - k2)];
        Am[idx] = s;
    }
    __syncthreads();
    if (tid == 0) {
        float s = pw3b[61];
        for (int c2 = 0; c2 < CC; ++c2) s += vals[c2];
        *beff = s;
    }
    for (int idx = tid; idx < CC * 45; idx += 1024) {
        int c0 = idx / 45, m = idx - c0 * 45;
        float s = 0.f;
        for (int c1 = 0; c1 < CC; ++c1) s += pw1[c1 * CC + c0] * Am[c1 * 45 + m];
        Bmg[idx] = s;
    }
}

// ---------------- setup stage 2 (64 blocks): Ftb[o][c0] ----------------
__global__ __launch_bounds__(128) void k_setupF(
        const float* __restrict__ Bmg, const float* __restrict__ dw1,
        unsigned short* __restrict__ Ftb) {
    __shared__ float Bl[45];
    int c0 = blockIdx.x;
    int o = threadIdx.x;
    if (c0 < CC && o < 45) Bl[o] = Bmg[c0 * 45 + o];
    __syncthreads();
    if (o >= 112) return;
    float s = 0.f;
    if (c0 < CC && o < FLEN) {
        int mlo = max(0, o - (KK1 - 1));
        int mhi = min(44, o);
        for (int m = mlo; m <= mhi; ++m)
            s += Bl[m] * dw1[c0 * KK1 + (o - m)];
    }
    Ftb[o * 64 + c0] = f2bf(s);
}

// ---------------- main: one block per (b,t) ----------------
// Wave-private coalesced staging: wave w owns pair-groups {w, w+4, w+8, w+12}
// (group g = channel-pairs 2g, 2g+1). Coalesced dwordx2 loads -> regs (double-
// buffered) -> wave-private LDS chunk -> transpose/pack -> swizzled xT.
// NO block barriers during staging; only intra-wave lgkmcnt + counted vmcnt.
#define CH_ISSUE(g, s) do {                                                        \
    const uint2* p0 = (const uint2*)(xg + 338 * (2 * (g)));                        \
    const uint2* p1 = (const uint2*)(xg + 338 * (2 * (g) + 1 > 30 ? 30 : 2 * (g) + 1)); \
    _Pragma("unroll")                                                              \
    for (int j = 0; j < 3; ++j) {                                                  \
        int pos = lane + 64 * j; if (pos > 168) pos = 168;                         \
        asm volatile("global_load_dwordx2 %0, %1, off"                             \
                     : "=v"(RG[s][j]) : "v"(p0 + pos));                            \
        asm volatile("global_load_dwordx2 %0, %1, off"                             \
                     : "=v"(RG[s][3 + j]) : "v"(p1 + pos));                        \
    }                                                                              \
} while (0)

#define CH_CONSUME(g, s, VM) do {                                                  \
    asm volatile("s_waitcnt vmcnt(" VM ")"                                         \
        : "+v"(RG[s][0]), "+v"(RG[s][1]), "+v"(RG[s][2]),                          \
          "+v"(RG[s][3]), "+v"(RG[s][4]), "+v"(RG[s][5]));                         \
    {                                                                              \
        uint2* cb2 = (uint2*)(chunkbuf + wid * 2704);                              \
        _Pragma("unroll")                                                          \
        for (int j = 0; j < 3; ++j) {                                              \
            int pos = lane + 64 * j; if (pos > 168) pos = 168;                     \
            cb2[pos] = RG[s][j];                                                   \
            cb2[169 + pos] = RG[s][3 + j];                                         \
        }                                                                          \
    }                                                                              \
    asm volatile("s_waitcnt lgkmcnt(0)" ::: "memory");                             \
    __builtin_amdgcn_sched_barrier(0);                                             \
    {                                                                              \
        int cpL = lane >> 5, lb = lane & 31;                                       \
        int cp = 2 * (g) + cpL;                                                    \
        if (cp < 31) {                                                             \
            const unsigned* cbf = (const unsigned*)(chunkbuf + wid * 2704);        \
            int base = cpL * 338;                                                  \
            _Pragma("unroll")                                                      \
            for (int it = 0; it < 6; ++it) {                                       \
                int l = lb + 32 * it;                                              \
                if (l < LL) {                                                      \
                    unsigned lo = cbf[base + l];                                   \
                    unsigned hi = cbf[base + 169 + l];                             \
                    unsigned v;                                                    \
                    asm("v_cvt_pk_bf16_f32 %0, %1, %2" : "=v"(v)                   \
                        : "v"(__uint_as_float(lo)), "v"(__uint_as_float(hi)));     \
                    xTu[(l * 32 + cp) ^ ((l & 7) << 2)] = v;                       \
                }                                                                  \
            }                                                                      \
        }                                                                          \
    }                                                                              \
    asm volatile("s_waitcnt lgkmcnt(0)" ::: "memory");                             \
    __builtin_amdgcn_sched_barrier(0);                                             \
} while (0)

__global__ __launch_bounds__(256, 3) void k_main(
        const float* __restrict__ x, const float* __restrict__ adj,
        const unsigned short* __restrict__ Ftb, const float* __restrict__ beff_p,
        const float* __restrict__ gcnw, const float* __restrict__ gcnb,
        const float* __restrict__ WtAll, const float* __restrict__ bias192,
        float* __restrict__ gates) {
    __shared__ __align__(16) unsigned short xT[176 * 64];   // 22528 B swizzled [l][c] bf16
    __shared__ __align__(16) char chunkbuf[4 * 2704];       // 10816 B wave-private f32 chunks
    __shared__ float dacc[4][64];
    __shared__ __align__(16) unsigned adjbf[32];
    __shared__ float wxl[176];
    __shared__ float gpart[4][64];
    __shared__ float Gl[64];
    int bt = blockIdx.x;
    int tid = threadIdx.x;
    int lane = tid & 63, wid = tid >> 6;
    int col = lane & 15, rb4 = lane >> 4;
    unsigned* xTu = (unsigned*)xT;
    const float* xg = x + (size_t)bt * (CC * LL);

    // aux loads FIRST (older vmcnt entries -> counted waits stay sufficient)
    float be = *beff_p;                                        // SMEM
    float2 arow2 = make_float2(0.f, 0.f);
    if (tid < 31) arow2 = *(const float2*)(adj + 61 * CC + 2 * tid);
    const unsigned short* ap0 = Ftb + ((wid * 16 + col) * 64 + rb4 * 8);
    s16x8 pa0 = *(const s16x8*)ap0;
    s16x8 pa1 = *(const s16x8*)(ap0 + 32);
    int mt2c = wid + 4 < 7 ? wid + 4 : 6;
    const unsigned short* ap1 = Ftb + ((mt2c * 16 + col) * 64 + rb4 * 8);
    s16x8 pb0 = *(const s16x8*)(ap1);
    s16x8 pb1 = *(const s16x8*)(ap1 + 32);
    __builtin_amdgcn_sched_barrier(0);

    // wave-private rolling pipeline over groups {wid, wid+4, wid+8, wid+12}
    uint2 RG[2][6];
    CH_ISSUE(wid, 0);
    CH_ISSUE(wid + 4, 1);
    // zero pads (col dword 31, rows>=169) + dacc while loads fly
    for (int i = tid; i < 169; i += 256) xTu[(i * 32 + 31) ^ ((i & 7) << 2)] = 0;
    for (int i = tid; i < 224; i += 256) {
        int r = 169 + (i >> 5), dd = i & 31;
        xTu[(r * 32 + dd) ^ ((r & 7) << 2)] = 0;
    }
    ((float*)dacc)[tid] = 0.f;

    CH_CONSUME(wid, 0, "6");      CH_ISSUE(wid + 8, 0);
    CH_CONSUME(wid + 4, 1, "6");  CH_ISSUE(wid + 12, 1);
    CH_CONSUME(wid + 8, 0, "6");
    CH_CONSUME(wid + 12, 1, "0");
    __syncthreads();

    // ---- band MFMA: wave wid handles mt in {wid, wid+4}; atomics -> dacc[rb4][j] ----
    // high-c half read is (bbyte ^ 64): bbyte already row-XOR'd; pre-swizzle bit6==0.
    f32x4 zacc[5];
    #pragma unroll
    for (int d = 0; d < 5; ++d) zacc[d] = (f32x4){0.f, 0.f, 0.f, 0.f};
    int kb = rb4 * 16;
    int xr = (lane & 7) << 4;
    #pragma unroll
    for (int h = 0; h < 2; ++h) {
        int mt = wid + 4 * h;
        if (mt < 7) {
            s16x8 a0 = h == 0 ? pa0 : pb0;
            s16x8 a1 = h == 0 ? pa1 : pb1;
            #pragma unroll
            for (int d = 0; d < 5; ++d) {
                int nt = mt + d;
                int bbyte = ((nt * 16 + col) * 128 + kb) ^ xr;
                s16x8 b0 = *(const s16x8*)((const char*)xT + bbyte);
                s16x8 b1 = *(const s16x8*)((const char*)xT + (bbyte ^ 64));
                zacc[d] = __builtin_amdgcn_mfma_f32_16x16x32_bf16(a0, b0, zacc[d], 0, 0, 0);
                zacc[d] = __builtin_amdgcn_mfma_f32_16x16x32_bf16(a1, b1, zacc[d], 0, 0, 0);
            }
        }
    }
    int jc = col - rb4 * 4;
    #pragma unroll
    for (int d = 0; d < 5; ++d) {
        #pragma unroll
        for (int r = 0; r < 4; ++r) {
            int j = 16 * d + jc - r;
            if ((unsigned)j < 62u) atomicAdd(&dacc[rb4][j], zacc[d][r]);
        }
    }
    __syncthreads();

    // ---- fused sigmoid + bf16 pack ----
    if (tid < 32) {
        unsigned pk = 0;
        if (tid < 31) {
            int j0 = 2 * tid;
            float2 g0 = *(const float2*)(&dacc[0][j0]);
            float2 g1 = *(const float2*)(&dacc[1][j0]);
            float2 g2 = *(const float2*)(&dacc[2][j0]);
            float2 g3 = *(const float2*)(&dacc[3][j0]);
            float dv0 = (g0.x + g1.x) + (g2.x + g3.x) + be + arow2.x;
            float dv1 = (g0.y + g1.y) + (g2.y + g3.y) + be + arow2.y;
            float s0 = 1.f / (1.f + __expf(-dv0));
            float s1 = 1.f / (1.f + __expf(-dv1));
            asm("v_cvt_pk_bf16_f32 %0, %1, %2" : "=v"(pk) : "v"(s0), "v"(s1));
        }
        adjbf[tid] = pk;
    }
    __syncthreads();

    // ---- wx via MFMA -> wxl (LDS) ----
    {
        s16x8 wa0 = *(const s16x8*)(adjbf + rb4 * 4);
        s16x8 wa1 = *(const s16x8*)(adjbf + 16 + rb4 * 4);
        #pragma unroll
        for (int q = 0; q < 3; ++q) {
            int nt = wid + 4 * q;
            if (nt < 11) {
                int bbyte = ((nt * 16 + col) * 128 + kb) ^ xr;
                s16x8 b0 = *(const s16x8*)((const char*)xT + bbyte);
                s16x8 b1 = *(const s16x8*)((const char*)xT + (bbyte ^ 64));
                f32x4 wacc = {0.f, 0.f, 0.f, 0.f};
                wacc = __builtin_amdgcn_mfma_f32_16x16x32_bf16(wa0, b0, wacc, 0, 0, 0);
                wacc = __builtin_amdgcn_mfma_f32_16x16x32_bf16(wa1, b1, wacc, 0, 0, 0);
                if (rb4 == 0) wxl[nt * 16 + col] = wacc[0];
            }
        }
    }
    __syncthreads();

    // ---- G = wx @ gcn_w + gcn_b (in-block, weights from L2) ----
    {
        int f = tid & 63, lq = tid >> 6;
        float s = 0.f;
        for (int l = lq; l < LL; l += 4) s += wxl[l] * gcnw[l * OG + f];
        gpart[lq][f] = s;
    }
    __syncthreads();
    if (tid < OG)
        Gl[tid] = gcnb[tid] + gpart[0][tid] + gpart[1][tid] + gpart[2][tid] + gpart[3][tid];
    __syncthreads();

    // ---- gates[bt][192] = G @ W^T + biases (coalesced global write) ----
    if (tid < 192) {
        float s = bias192[tid];
        #pragma unroll 16
        for (int k = 0; k < OG; ++k) s += Gl[k] * WtAll[k * 192 + tid];
        gates[(size_t)bt * 192 + tid] = s;
    }
}

// ---------------- sequential GRU scan over t: one block per batch row ----------------
__global__ __launch_bounds__(256) void k_scan(
        const float* __restrict__ gates,
        const float* __restrict__ Wr, const float* __restrict__ Wu, const float* __restrict__ Wc,
        float* __restrict__ out) {
    __shared__ float hl[OH], rhl[OH];
    int b = blockIdx.x;
    int tid = threadIdx.x;
    int f = tid >> 2, q = tid & 3;
    float wr[16], wu[16], wc[16];
    #pragma unroll
    for (int i = 0; i < 16; ++i) {
        int col = OG + q * 16 + i;
        wr[i] = Wr[f * (OG + OH) + col];
        wu[i] = Wu[f * (OG + OH) + col];
        wc[i] = Wc[f * (OG + OH) + col];
    }
    float h = 0.f;
    if (tid < OH) hl[tid] = 0.f;
    __syncthreads();
    for (int t = 0; t < SS; ++t) {
        const float* gp = gates + ((size_t)b * SS + t) * 192;
        float gr = gp[f];
        float gu = gp[64 + f];
        float gc = gp[128 + f];
        float rv = 0.f, uv = 0.f;
        #pragma unroll
        for (int i = 0; i < 16; ++i) {
            float hv = hl[q * 16 + i];
            rv += wr[i] * hv;
            uv += wu[i] * hv;
        }
        rv += __shfl_xor(rv, 1); rv += __shfl_xor(rv, 2);
        uv += __shfl_xor(uv, 1); uv += __shfl_xor(uv, 2);
        float r = 1.f / (1.f + __expf(-(rv + gr)));
        float u = 1.f / (1.f + __expf(-(uv + gu)));
        if (q == 0) rhl[f] = r * h;
        __syncthreads();
        float cv = 0.f;
        #pragma unroll
        for (int i = 0; i < 16; ++i) cv += wc[i] * rhl[q * 16 + i];
        cv += __shfl_xor(cv, 1); cv += __shfl_xor(cv, 2);
        float cc = tanhf(cv + gc);
        if (q == 0) {
            h = u * h + (1.f - u) * cc;
            hl[f] = h;
        }
        __syncthreads();
    }
    if (q == 0) out[b * OH + f] = h;
}

extern "C" void kernel_launch(void* const* d_in, const int* in_sizes, int n_in,
                              void* d_out, int out_size, void* d_ws, size_t ws_size,
                              hipStream_t stream) {
    const float* x    = (const float*)d_in[0];
    const float* adj  = (const float*)d_in[1];
    const float* dw1w = (const float*)d_in[2];
    const float* dw1b = (const float*)d_in[3];
    const float* pw1w = (const float*)d_in[4];
    const float* pw1b = (const float*)d_in[5];
    const float* dw2w = (const float*)d_in[6];
    const float* dw2b = (const float*)d_in[7];
    const float* pw2w = (const float*)d_in[8];
    const float* pw2b = (const float*)d_in[9];
    const float* dw3w = (const float*)d_in[10];
    const float* dw3b = (const float*)d_in[11];
    const float* pw3w = (const float*)d_in[12];
    const float* pw3b = (const float*)d_in[13];
    const float* gcnw = (const float*)d_in[14];
    const float* gcnb = (const float*)d_in[15];
    const float* Wrw  = (const float*)d_in[16];
    const float* Wrb  = (const float*)d_in[17];
    const float* Wuw  = (const float*)d_in[18];
    const float* Wub  = (const float*)d_in[19];
    const float* Wcw  = (const float*)d_in[20];
    const float* Wcb  = (const float*)d_in[21];
    const float* br   = (const float*)d_in[22];
    const float* bu   = (const float*)d_in[23];
    const float* bc   = (const float*)d_in[24];
    float* out = (float*)d_out;

    char* ws = (char*)d_ws;
    unsigned short* Ftb = (unsigned short*)(ws + 0);        // 14336 B
    float* WtAll        = (float*)(ws + 14336);             // 49152 B
    float* bias192      = (float*)(ws + 63488);             // 768 B
    float* beff         = (float*)(ws + 64256);             // 4 B
    float* Bmg          = (float*)(ws + 64320);             // 11160 B
    float* gates        = (float*)(ws + 76800);             // 7680*192*4 = 5898240 B
    (void)ws_size; (void)in_sizes; (void)n_in; (void)out_size;

    k_setup1<<<1, 1024, 0, stream>>>(dw1w, dw1b, pw1w, pw1b, dw2w, dw2b, pw2w, pw2b,
                                     dw3w, dw3b, pw3w, pw3b,
                                     Wrw, Wrb, br, Wuw, Wub, bu, Wcw, Wcb, bc,
                                     Bmg, WtAll, bias192, beff);
    k_setupF<<<64, 128, 0, stream>>>(Bmg, dw1w, Ftb);
    k_main<<<BB * SS, 256, 0, stream>>>(x, adj, Ftb, beff, gcnw, gcnb,
                                        WtAll, bias192, gates);
    k_scan<<<BB, 256, 0, stream>>>(gates, Wrw, Wuw, Wcw, out);
}